// Round 4
// baseline (473.131 us; speedup 1.0000x reference)
//
#include <hip/hip_runtime.h>

#define B_    256
#define N_    256
#define DIN   768
#define DOUT  300
#define DOUTP 320           // padded to 20*16
#define M_    (B_*N_)       // 65536
#define HP_ELEMS (M_*DOUT)  // 19660800
#define NEG_INF -9.0e15f

typedef _Float16 f16;
typedef __attribute__((ext_vector_type(8))) _Float16 f16x8;
typedef __attribute__((ext_vector_type(4))) _Float16 f16x4;
typedef __attribute__((ext_vector_type(4))) float    f32x4;

// ---- kernel 0: WtT[kt][n][k'] = f16(W[kt*32+k'][n]), linear, pad n>=300 ----
__global__ __launch_bounds__(256) void prep_wt(const float* __restrict__ W,
                                               f16* __restrict__ WtT) {
    int idx = blockIdx.x * 256 + threadIdx.x;      // over DIN*DOUTP
    if (idx >= DIN * DOUTP) return;
    int k = idx / DOUTP, n = idx - k * DOUTP;
    float v = (n < DOUT) ? W[k * DOUT + n] : 0.0f;
    WtT[(((size_t)(k >> 5) * DOUTP + n) << 5) + (k & 31)] = (f16)v;
}

// ---- kernel 1: Wh = h@W + pos; f_src/f_dst; WhT2 (k-tiled linear) ---------
// grid 1024 strips of 64 rows, 256 threads (4 waves).
// ZERO barriers in the K-loop: B fragments load direct global->reg from
// L2-resident WtT (coalesced 1KB/inst), double-buffered, static-indexed.
// A (h) converted f32->f16 into swizzled LDS once per K-half (only syncs).
__global__ __launch_bounds__(256, 3) void gemm1(
    const float* __restrict__ h, const f16* __restrict__ WtT,
    const int* __restrict__ positions,
    const float* __restrict__ a_src, const float* __restrict__ a_dst,
    const float* __restrict__ pos_table,
    f16* __restrict__ WhT2, float* __restrict__ f_src, float* __restrict__ f_dst)
{
    __shared__ f16 Ah[64 * 384];       // 48 KB: 64 rows x one K-half, XOR-swizzled
    __shared__ float pfs[64][4], pfd[64][4];

    const int tid  = threadIdx.x;
    const int wave = tid >> 6, lane = tid & 63;
    const int quad = lane >> 4, c = lane & 15;
    const int rowbase = blockIdx.x * 64;
    const int cx7 = c & 7;

    // convert-phase mapping: 4 threads/row, 12 chunks of 8 f32 each
    const int crow = tid >> 2, cl4 = tid & 3;
    const float* cbase = h + (size_t)(rowbase + crow) * DIN;

    // per-wave B fragment offsets (f16 elements within a k-tile)
    int boffs[5];
#pragma unroll
    for (int i = 0; i < 5; ++i) {
        int n = (wave * 5 + i) * 16 + c;
        boffs[i] = (n << 5) + (quad << 3);
    }

    f32x4 acc[4][5];
#pragma unroll
    for (int rt = 0; rt < 4; ++rt)
#pragma unroll
        for (int i = 0; i < 5; ++i) acc[rt][i] = (f32x4){0.f, 0.f, 0.f, 0.f};

    f16x8 bs[2][5];   // static-indexed only (full unroll below)

#define CONV(HALF) do {                                                        \
    _Pragma("unroll")                                                          \
    for (int j_ = 0; j_ < 12; ++j_) {                                          \
        int c8_ = j_ * 4 + cl4;                                                \
        const float4* s_ = (const float4*)(cbase + (HALF) * 384 + c8_ * 8);    \
        float4 v0 = s_[0], v1 = s_[1];                                         \
        int slot_ = c8_ ^ (crow & 7);                                          \
        *(f16x8*)&Ah[crow * 384 + slot_ * 8] =                                 \
            (f16x8){(f16)v0.x, (f16)v0.y, (f16)v0.z, (f16)v0.w,                \
                    (f16)v1.x, (f16)v1.y, (f16)v1.z, (f16)v1.w};               \
    } } while (0)

#define PREF(KT, S) do {                                                       \
    const f16* p_ = WtT + (size_t)(KT) * (DOUTP * 32);                         \
    _Pragma("unroll")                                                          \
    for (int i_ = 0; i_ < 5; ++i_)                                             \
        bs[S][i_] = *(const f16x8*)(p_ + boffs[i_]);                           \
    } while (0)

#define COMPUTE(KT12, S) do {                                                  \
    const int k4_ = (KT12) * 4 + quad;                                         \
    __builtin_amdgcn_s_setprio(1);                                             \
    _Pragma("unroll")                                                          \
    for (int rt_ = 0; rt_ < 4; ++rt_) {                                        \
        f16x8 af = *(const f16x8*)&Ah[(rt_ * 16 + c) * 384 + ((k4_ ^ cx7) << 3)]; \
        _Pragma("unroll")                                                      \
        for (int i_ = 0; i_ < 5; ++i_)                                         \
            acc[rt_][i_] = __builtin_amdgcn_mfma_f32_16x16x32_f16(             \
                af, bs[S][i_], acc[rt_][i_], 0, 0, 0);                         \
    }                                                                          \
    __builtin_amdgcn_s_setprio(0);                                             \
    } while (0)

    CONV(0);
    __syncthreads();
    PREF(0, 0);
#pragma unroll
    for (int kt2 = 0; kt2 < 12; ++kt2) {
        const int ktA = 2 * kt2, ktB = 2 * kt2 + 1;
        PREF(ktB, 1);
        COMPUTE(ktA % 12, 0);
        if (ktB + 1 < 24) PREF(ktB + 1, 0);
        COMPUTE(ktB % 12, 1);
        if (kt2 == 5) {          // half boundary: all reads of Ah half0 done
            __syncthreads();
            CONV(1);
            __syncthreads();
        }
    }
#undef COMPUTE
#undef PREF
#undef CONV

    // ---- epilogue: pos add, f_src/f_dst, WhT2 store (k-tiled linear) ----
    const int bidx = rowbase >> 8;
    const int ktb0 = (rowbase & 255) >> 5;       // 64 rows span 2 k-tiles

    int posr[4][4];
#pragma unroll
    for (int rt = 0; rt < 4; ++rt)
#pragma unroll
        for (int r = 0; r < 4; ++r)
            posr[rt][r] = positions[rowbase + rt * 16 + quad * 4 + r];

    float fs[4][4], fd[4][4];
#pragma unroll
    for (int rt = 0; rt < 4; ++rt)
#pragma unroll
        for (int r = 0; r < 4; ++r) { fs[rt][r] = 0.f; fd[rt][r] = 0.f; }

#pragma unroll
    for (int i = 0; i < 5; ++i) {
        int col = (wave * 5 + i) * 16 + c;
        if (col < DOUT) {
            float as = a_src[col], ad = a_dst[col];
#pragma unroll
            for (int rt = 0; rt < 4; ++rt)
#pragma unroll
                for (int r = 0; r < 4; ++r) {
                    float v = acc[rt][i][r] + pos_table[posr[rt][r] * DOUT + col];
                    acc[rt][i][r] = v;
                    fs[rt][r] += v * as;
                    fd[rt][r] += v * ad;
                }
        } else {
#pragma unroll
            for (int rt = 0; rt < 4; ++rt)
#pragma unroll
                for (int r = 0; r < 4; ++r) acc[rt][i][r] = 0.0f;
        }
    }
#pragma unroll
    for (int off = 1; off < 16; off <<= 1) {
#pragma unroll
        for (int rt = 0; rt < 4; ++rt)
#pragma unroll
            for (int r = 0; r < 4; ++r) {
                fs[rt][r] += __shfl_xor(fs[rt][r], off, 16);
                fd[rt][r] += __shfl_xor(fd[rt][r], off, 16);
            }
    }
    if (c == 0) {
#pragma unroll
        for (int rt = 0; rt < 4; ++rt)
#pragma unroll
            for (int r = 0; r < 4; ++r) {
                int row = rt * 16 + quad * 4 + r;
                pfs[row][wave] = fs[rt][r];
                pfd[row][wave] = fd[rt][r];
            }
    }
    // WhT2[bidx][kt][col][k']: linear in k'
#pragma unroll
    for (int i = 0; i < 5; ++i) {
        int col = (wave * 5 + i) * 16 + c;
#pragma unroll
        for (int rt = 0; rt < 4; ++rt) {
            f16x4 u = (f16x4){(f16)acc[rt][i][0], (f16)acc[rt][i][1],
                              (f16)acc[rt][i][2], (f16)acc[rt][i][3]};
            size_t off = (((size_t)(bidx * 8 + ktb0 + (rt >> 1)) * DOUTP + col) << 5)
                         + (rt & 1) * 16 + quad * 4;
            *(f16x4*)(WhT2 + off) = u;
        }
    }
    __syncthreads();
    if (tid < 64) {
        f_src[rowbase + tid] = pfs[tid][0] + pfs[tid][1] + pfs[tid][2] + pfs[tid][3];
        f_dst[rowbase + tid] = pfd[tid][0] + pfd[tid][1] + pfd[tid][2] + pfd[tid][3];
    }
}

// ---- kernel 2: fused masked-softmax + h_prime = att @ Wh ------------------
// grid 1024 (64 rows/block), 256 threads. P in swizzled LDS; B fragments
// direct global->reg from WhT2 (coalesced), double-buffered; no GEMM barriers.
__global__ __launch_bounds__(256, 3) void fused2(
    const float* __restrict__ adj, const float* __restrict__ f_src,
    const float* __restrict__ f_dst, const f16* __restrict__ WhT2,
    float* __restrict__ att, float* __restrict__ hp)
{
    __shared__ f16 Pl[64 * 256];        // 32 KB, XOR-swizzled

    const int tid  = threadIdx.x;
    const int wave = tid >> 6, lane = tid & 63;
    const int quad = lane >> 4, c = lane & 15;
    const int rowbase = blockIdx.x * 64;
    const int bidx = rowbase >> 8;
    const int cx7 = c & 7;

    int boffs[5];
#pragma unroll
    for (int i = 0; i < 5; ++i) {
        int n = (wave * 5 + i) * 16 + c;
        boffs[i] = (n << 5) + (quad << 3);
    }
    const f16* wbase = WhT2 + (size_t)bidx * 8 * (DOUTP * 32);

    f16x8 bs[2][5];
#define PREF2(KT, S) do {                                                      \
    const f16* p_ = wbase + (size_t)(KT) * (DOUTP * 32);                       \
    _Pragma("unroll")                                                          \
    for (int i_ = 0; i_ < 5; ++i_)                                             \
        bs[S][i_] = *(const f16x8*)(p_ + boffs[i_]);                           \
    } while (0)

    // ---- phase 0: masked softmax for 64 rows; att out + P into LDS ----
    {
        float4 fd4 = *(const float4*)(f_dst + bidx * N_ + lane * 4);
        const float* arow = adj + (size_t)(rowbase + wave * 16) * N_ + lane * 4;
        float4 nx0 = *(const float4*)arow;
        float4 nx1 = *(const float4*)(arow + N_);
        for (int rr = 0; rr < 16; ++rr) {
            float4 a4 = nx0;
            nx0 = nx1;
            if (rr + 2 < 16) nx1 = *(const float4*)(arow + (size_t)(rr + 2) * N_);
            const int lrow = wave * 16 + rr;
            const int row  = rowbase + lrow;
            float fsv = f_src[row];

            float v, e0, e1, e2, e3;
            v = fsv + fd4.x; v = v >= 0.f ? v : 0.2f * v; e0 = a4.x > 0.f ? v : NEG_INF;
            v = fsv + fd4.y; v = v >= 0.f ? v : 0.2f * v; e1 = a4.y > 0.f ? v : NEG_INF;
            v = fsv + fd4.z; v = v >= 0.f ? v : 0.2f * v; e2 = a4.z > 0.f ? v : NEG_INF;
            v = fsv + fd4.w; v = v >= 0.f ? v : 0.2f * v; e3 = a4.w > 0.f ? v : NEG_INF;

            float mx = fmaxf(fmaxf(e0, e1), fmaxf(e2, e3));
#pragma unroll
            for (int off = 1; off < 64; off <<= 1) mx = fmaxf(mx, __shfl_xor(mx, off, 64));

            float p0 = __expf(e0 - mx), p1 = __expf(e1 - mx);
            float p2 = __expf(e2 - mx), p3 = __expf(e3 - mx);
            float s = p0 + p1 + p2 + p3;
#pragma unroll
            for (int off = 1; off < 64; off <<= 1) s += __shfl_xor(s, off, 64);

            float inv = 1.0f / s;
            *(float4*)(att + (size_t)row * N_ + lane * 4) =
                make_float4(p0 * inv, p1 * inv, p2 * inv, p3 * inv);
            int slot = (lane >> 1) ^ (lrow & 7);
            *(f16x4*)&Pl[lrow * 256 + slot * 8 + (lane & 1) * 4] =
                (f16x4){(f16)(p0 * inv), (f16)(p1 * inv), (f16)(p2 * inv), (f16)(p3 * inv)};
        }
    }
    PREF2(0, 0);
    __syncthreads();   // P visible — the only barrier

    // ---- phase 1: GEMM, A = P (LDS), B reg double-buffer, no barriers ----
    f32x4 acc[4][5];
#pragma unroll
    for (int rt = 0; rt < 4; ++rt)
#pragma unroll
        for (int i = 0; i < 5; ++i) acc[rt][i] = (f32x4){0.f, 0.f, 0.f, 0.f};

#define COMPUTE2(KT, S) do {                                                   \
    const int k4_ = (KT) * 4 + quad;                                           \
    __builtin_amdgcn_s_setprio(1);                                             \
    _Pragma("unroll")                                                          \
    for (int rt_ = 0; rt_ < 4; ++rt_) {                                        \
        f16x8 af = *(const f16x8*)&Pl[(rt_ * 16 + c) * 256 + ((k4_ ^ cx7) << 3)]; \
        _Pragma("unroll")                                                      \
        for (int i_ = 0; i_ < 5; ++i_)                                         \
            acc[rt_][i_] = __builtin_amdgcn_mfma_f32_16x16x32_f16(             \
                af, bs[S][i_], acc[rt_][i_], 0, 0, 0);                         \
    }                                                                          \
    __builtin_amdgcn_s_setprio(0);                                             \
    } while (0)

#pragma unroll
    for (int kt2 = 0; kt2 < 4; ++kt2) {
        const int ktA = 2 * kt2, ktB = 2 * kt2 + 1;
        PREF2(ktB, 1);
        COMPUTE2(ktA, 0);
        if (ktB + 1 < 8) PREF2(ktB + 1, 0);
        COMPUTE2(ktB, 1);
    }
#undef COMPUTE2
#undef PREF2

    // epilogue: hp[row][col], col<300
#pragma unroll
    for (int i = 0; i < 5; ++i) {
        int col = (wave * 5 + i) * 16 + c;
        if (col < DOUT) {
#pragma unroll
            for (int rt = 0; rt < 4; ++rt) {
                int row0 = rowbase + rt * 16 + quad * 4;
#pragma unroll
                for (int r = 0; r < 4; ++r)
                    hp[(size_t)(row0 + r) * DOUT + col] = acc[rt][i][r];
            }
        }
    }
}

extern "C" void kernel_launch(void* const* d_in, const int* in_sizes, int n_in,
                              void* d_out, int out_size, void* d_ws, size_t ws_size,
                              hipStream_t stream)
{
    const float* h         = (const float*)d_in[0];
    const float* adj       = (const float*)d_in[1];
    const int*   positions = (const int*)d_in[2];
    const float* W         = (const float*)d_in[3];
    const float* a_src     = (const float*)d_in[4];
    const float* a_dst     = (const float*)d_in[5];
    const float* pos_table = (const float*)d_in[6];

    float* hp  = (float*)d_out;            // [65536][300]
    float* att = hp + HP_ELEMS;            // [65536][256]

    f16*   WtT   = (f16*)d_ws;                         // [24][320][32]
    f16*   WhT2  = WtT + (size_t)DOUTP * DIN;          // [256*8][320][32]
    float* f_src = (float*)(WhT2 + (size_t)B_ * DOUTP * N_);
    float* f_dst = f_src + M_;

    hipLaunchKernelGGL(prep_wt, dim3((DIN * DOUTP + 255) / 256), dim3(256), 0, stream, W, WtT);
    hipLaunchKernelGGL(gemm1,   dim3(M_ / 64), dim3(256), 0, stream,
                       h, WtT, positions, a_src, a_dst, pos_table, WhT2, f_src, f_dst);
    hipLaunchKernelGGL(fused2,  dim3(M_ / 64), dim3(256), 0, stream,
                       adj, f_src, f_dst, WhT2, att, hp);
}